// Round 3
// baseline (3824.595 us; speedup 1.0000x reference)
//
#include <hip/hip_runtime.h>

#define B_ 4
#define S_ 2048
#define H_ 1024
#define L_ 4
#define N_ 4
#define D_ 256
#define V_ 256
#define EPSF 1e-5f

typedef __attribute__((ext_vector_type(8))) short short8;
typedef __attribute__((ext_vector_type(4))) float f32x4;

__device__ inline float bf2f(unsigned short u) {
    union { unsigned int ui; float f; } c; c.ui = ((unsigned int)u) << 16; return c.f;
}
__device__ inline unsigned short f2bf(float f) {
    union { float f; unsigned int ui; } c; c.f = f;
    unsigned int u = c.ui;
    unsigned int r = (u + 0x7FFFu + ((u >> 16) & 1u)) >> 16;
    return (unsigned short)r;
}
__device__ inline float wave64_sum(float v) {
    for (int m = 32; m >= 1; m >>= 1) v += __shfl_xor(v, m, 64);
    return v;
}

// ---------------------------------------------------------------------------
// fp32 -> bf16 weight convert, 8 elements/thread
// ---------------------------------------------------------------------------
__global__ void wcvt_kernel(const float* __restrict__ W,
                            unsigned short* __restrict__ Wb, int n8) {
    int idx = blockIdx.x * 256 + threadIdx.x;
    if (idx >= n8) return;
    size_t base = (size_t)idx * 8;
    float4 a0 = *(const float4*)(W + base);
    float4 a1 = *(const float4*)(W + base + 4);
    short8 t;
    t[0] = f2bf(a0.x); t[1] = f2bf(a0.y); t[2] = f2bf(a0.z); t[3] = f2bf(a0.w);
    t[4] = f2bf(a1.x); t[5] = f2bf(a1.y); t[6] = f2bf(a1.z); t[7] = f2bf(a1.w);
    *(short8*)(Wb + base) = t;
}

// ---------------------------------------------------------------------------
// Embedding gather: fp32 embed -> bf16 X
// ---------------------------------------------------------------------------
__global__ void gather_kernel(const int* __restrict__ ids,
                              const float* __restrict__ embed,
                              unsigned short* __restrict__ x) {
    size_t idx = (size_t)blockIdx.x * 256 + threadIdx.x;   // T total
    int bs = (int)(idx >> 10);
    int h  = (int)(idx & 1023);
    x[idx] = f2bf(embed[(size_t)ids[bs] * H_ + h]);
}

// ---------------------------------------------------------------------------
// Column mean (accumulated as sum into fp32, divided later)
// grid (B*H/256, 16): y covers s-chunks of 128
// ---------------------------------------------------------------------------
__global__ void mean_kernel(const unsigned short* __restrict__ Xin,
                            float* __restrict__ xmean) {
    int idx = blockIdx.x * 256 + threadIdx.x;   // 0 .. B*H-1
    int b = idx >> 10, h = idx & 1023;
    int s0 = blockIdx.y * 128;
    const unsigned short* p = Xin + ((size_t)b * S_ + s0) * H_ + h;
    float s = 0.f;
    for (int i = 0; i < 128; i++) s += bf2f(p[(size_t)i * H_]);
    atomicAdd(&xmean[idx], s);
}

// nm: dopnor[b*2+j] = dot(xmean[b]/S, nm_ctx_w[j]) + nm_ctx_b[j]   (fp32 w,b)
__global__ void nm_kernel(const float* __restrict__ xmean,
                          const float* __restrict__ w,
                          const float* __restrict__ bias,
                          float* __restrict__ dopnor) {
    int wave = threadIdx.x >> 6, lane = threadIdx.x & 63;
    for (int p = wave; p < 2 * B_; p += 4) {
        int b = p >> 1, j = p & 1;
        float s = 0.f;
        for (int h = lane; h < H_; h += 64) s += xmean[b * H_ + h] * w[j * H_ + h];
        s = wave64_sum(s);
        if (lane == 0) dopnor[p] = s / (float)S_ + bias[j];
    }
}

// gain: qscale[b*N+n] = (1 + dot(xmean[b]/S, gw[n]) + gb[n]) / sqrt(D)  (fp32)
__global__ void gain_kernel(const float* __restrict__ xmean,
                            const float* __restrict__ gw,
                            const float* __restrict__ gb,
                            float* __restrict__ qscale) {
    int wave = threadIdx.x >> 6, lane = threadIdx.x & 63;
    for (int p = wave; p < B_ * N_; p += 4) {
        int b = p >> 2, n = p & 3;
        float s = 0.f;
        for (int h = lane; h < H_; h += 64) s += xmean[b * H_ + h] * gw[n * H_ + h];
        s = wave64_sum(s);
        if (lane == 0) qscale[p] = (1.f + s / (float)S_ + gb[n]) * 0.0625f;
    }
}

// ---------------------------------------------------------------------------
// GEMM: C(MxN) = epilogue( A(MxK) @ W(NxK)^T + bias )
// A bf16 (ws), W bf16 (pre-converted), bias fp32.
// block 256 thr = 4 waves (2x2), wave = 64x64 via 4x4 mfma_f32_16x16x32_bf16.
// modes: 0 plain->bf16; 1 gate: X*(1+dop[b]*sigmoid(g)); 2 noise: X+nor[b]*tanh(g);
//        3 residual: g+X; 4 silu(g); 5 plain->fp32.
// ---------------------------------------------------------------------------
__global__ __launch_bounds__(256) void gemm_bt(
    const unsigned short* __restrict__ A, const unsigned short* __restrict__ W,
    const float* __restrict__ bias, void* __restrict__ Cout,
    const unsigned short* __restrict__ X, const float* __restrict__ scal,
    int K, int Nout, int mode) {
    int tid = threadIdx.x;
    int wave = tid >> 6, lane = tid & 63;
    int quad = lane >> 4, l16 = lane & 15;
    int bm = blockIdx.x * 128 + (wave >> 1) * 64;
    int bn = blockIdx.y * 128 + (wave & 1) * 64;

    f32x4 acc[4][4];
#pragma unroll
    for (int i = 0; i < 4; i++)
#pragma unroll
        for (int j = 0; j < 4; j++)
#pragma unroll
            for (int r = 0; r < 4; r++) acc[i][j][r] = 0.f;

    for (int kk = 0; kk < K; kk += 32) {
        short8 af[4], bfr[4];
#pragma unroll
        for (int i = 0; i < 4; i++)
            af[i] = *(const short8*)(A + (size_t)(bm + i * 16 + l16) * K + kk + quad * 8);
#pragma unroll
        for (int j = 0; j < 4; j++)
            bfr[j] = *(const short8*)(W + (size_t)(bn + j * 16 + l16) * K + kk + quad * 8);
#pragma unroll
        for (int i = 0; i < 4; i++)
#pragma unroll
            for (int j = 0; j < 4; j++)
                acc[i][j] = __builtin_amdgcn_mfma_f32_16x16x32_bf16(af[i], bfr[j], acc[i][j], 0, 0, 0);
    }

#pragma unroll
    for (int i = 0; i < 4; i++) {
#pragma unroll
        for (int j = 0; j < 4; j++) {
            int col = bn + j * 16 + l16;
            float bv = bias ? bias[col] : 0.f;
#pragma unroll
            for (int r = 0; r < 4; r++) {
                int row = bm + i * 16 + quad * 4 + r;
                float v = acc[i][j][r] + bv;
                size_t off = (size_t)row * Nout + col;
                if (mode == 5) {
                    ((float*)Cout)[off] = v;
                    continue;
                }
                float outv;
                if (mode == 0) {
                    outv = v;
                } else if (mode == 1) {
                    float sig = 1.f / (1.f + __expf(-v));
                    float dop = scal[(row >> 11) * 2];
                    outv = bf2f(X[off]) * (1.f + dop * sig);
                } else if (mode == 2) {
                    float nor = scal[(row >> 11) * 2 + 1];
                    outv = bf2f(X[off]) + nor * tanhf(v);
                } else if (mode == 3) {
                    outv = v + bf2f(X[off]);
                } else {
                    outv = v * (1.f / (1.f + __expf(-v)));
                }
                ((unsigned short*)Cout)[off] = f2bf(outv);
            }
        }
    }
}

// ---------------------------------------------------------------------------
// Flash attention: per (b,n), Q-tile of 64 rows/block (16/wave), TK=32.
// Gain*(1/sqrt(D)) applied to scores. Output written in-place to O (== Q buffer).
// ---------------------------------------------------------------------------
__global__ __launch_bounds__(256) void flash_attn(
    const unsigned short* __restrict__ Q, const unsigned short* __restrict__ Kg,
    const unsigned short* __restrict__ Vg, const float* __restrict__ qscale,
    unsigned short* __restrict__ O) {
    __shared__ unsigned short Klds[32][264];    // t x d, row 528B
    __shared__ unsigned short Vt[256][40];      // d x t, row 80B
    __shared__ unsigned short Plds[4][16][40];  // per-wave P: m x t

    int tid = threadIdx.x;
    int wave = tid >> 6, lane = tid & 63;
    int quad = lane >> 4, l16 = lane & 15;
    int bnh = blockIdx.y;          // b*N + n
    int b = bnh >> 2, n = bnh & 3;
    size_t base = ((size_t)b * S_) * H_ + (size_t)n * D_;
    int q0 = blockIdx.x * 64 + wave * 16;
    float scale = qscale[bnh];

    // Q fragments (8 k-steps of 32)
    short8 qf[8];
#pragma unroll
    for (int kk = 0; kk < 8; kk++)
        qf[kk] = *(const short8*)(Q + base + (size_t)(q0 + l16) * H_ + kk * 32 + quad * 8);

    f32x4 o[16];
#pragma unroll
    for (int c = 0; c < 16; c++)
#pragma unroll
        for (int r = 0; r < 4; r++) o[c][r] = 0.f;
    float mrow[4] = {-1e30f, -1e30f, -1e30f, -1e30f};
    float lrow[4] = {0.f, 0.f, 0.f, 0.f};

    int srow = tid >> 3;           // 0..31
    int scol = (tid & 7) * 32;     // 0..224

    for (int t0 = 0; t0 < S_; t0 += 32) {
        __syncthreads();  // prior iteration's readers done
#pragma unroll
        for (int c = 0; c < 32; c += 8) {
            *(short8*)&Klds[srow][scol + c] =
                *(const short8*)(Kg + base + (size_t)(t0 + srow) * H_ + scol + c);
            short8 vv = *(const short8*)(Vg + base + (size_t)(t0 + srow) * H_ + scol + c);
#pragma unroll
            for (int e = 0; e < 8; e++) Vt[scol + c + e][srow] = vv[e];
        }
        __syncthreads();

        // scores S = Q K^T (16 x 32) as 2 col-tiles
        f32x4 s[2];
#pragma unroll
        for (int j = 0; j < 2; j++)
#pragma unroll
            for (int r = 0; r < 4; r++) s[j][r] = 0.f;
#pragma unroll
        for (int kk = 0; kk < 8; kk++) {
#pragma unroll
            for (int j = 0; j < 2; j++) {
                short8 kf = *(const short8*)&Klds[j * 16 + l16][kk * 32 + quad * 8];
                s[j] = __builtin_amdgcn_mfma_f32_16x16x32_bf16(qf[kk], kf, s[j], 0, 0, 0);
            }
        }

        // online softmax (row quad*4+r lives in this quad's 16 lanes)
        float alpha[4];
#pragma unroll
        for (int r = 0; r < 4; r++) {
            float s0 = s[0][r] * scale;
            float s1 = s[1][r] * scale;
            float mx = fmaxf(s0, s1);
            for (int m = 8; m >= 1; m >>= 1) mx = fmaxf(mx, __shfl_xor(mx, m, 64));
            float mnew = fmaxf(mrow[r], mx);
            alpha[r] = __expf(mrow[r] - mnew);
            mrow[r] = mnew;
            float p0 = __expf(s0 - mnew);
            float p1 = __expf(s1 - mnew);
            float rs = p0 + p1;
            for (int m = 8; m >= 1; m >>= 1) rs += __shfl_xor(rs, m, 64);
            lrow[r] = lrow[r] * alpha[r] + rs;
            Plds[wave][quad * 4 + r][l16]      = f2bf(p0);
            Plds[wave][quad * 4 + r][16 + l16] = f2bf(p1);
        }
#pragma unroll
        for (int c = 0; c < 16; c++)
#pragma unroll
            for (int r = 0; r < 4; r++) o[c][r] *= alpha[r];

        // O += P V  (P 16x32 from LDS in A-layout; V from transposed LDS)
        short8 pf = *(const short8*)&Plds[wave][l16][quad * 8];
#pragma unroll
        for (int c = 0; c < 16; c++) {
            short8 vf = *(const short8*)&Vt[c * 16 + l16][quad * 8];
            o[c] = __builtin_amdgcn_mfma_f32_16x16x32_bf16(pf, vf, o[c], 0, 0, 0);
        }
    }

    float invl[4];
#pragma unroll
    for (int r = 0; r < 4; r++) invl[r] = 1.f / lrow[r];
#pragma unroll
    for (int c = 0; c < 16; c++)
#pragma unroll
        for (int r = 0; r < 4; r++) {
            int row = q0 + quad * 4 + r;
            int d = c * 16 + l16;
            O[base + (size_t)row * H_ + d] = f2bf(o[c][r] * invl[r]);
        }
}

// ---------------------------------------------------------------------------
// Fused t = xe + y1 + y2; LayerNorm(t) * g + b  -> out (bf16); g,b fp32
// ---------------------------------------------------------------------------
__global__ __launch_bounds__(256) void ln_kernel(
    const unsigned short* __restrict__ xe, const unsigned short* __restrict__ y1,
    const unsigned short* __restrict__ y2, const float* __restrict__ g,
    const float* __restrict__ bta, unsigned short* __restrict__ out) {
    int row = blockIdx.x;
    size_t ro = (size_t)row * H_;
    int tid = threadIdx.x;
    float t[4]; float s = 0.f, s2 = 0.f;
#pragma unroll
    for (int i = 0; i < 4; i++) {
        int h = i * 256 + tid;
        float v = bf2f(xe[ro + h]) + bf2f(y1[ro + h]) + bf2f(y2[ro + h]);
        t[i] = v; s += v; s2 += v * v;
    }
    s = wave64_sum(s); s2 = wave64_sum(s2);
    __shared__ float sh[8];
    int wave = tid >> 6, lane = tid & 63;
    if (lane == 0) { sh[wave] = s; sh[4 + wave] = s2; }
    __syncthreads();
    s  = sh[0] + sh[1] + sh[2] + sh[3];
    s2 = sh[4] + sh[5] + sh[6] + sh[7];
    float mu = s * (1.f / H_);
    float var = s2 * (1.f / H_) - mu * mu;
    float inv = rsqrtf(var + EPSF);
#pragma unroll
    for (int i = 0; i < 4; i++) {
        int h = i * 256 + tid;
        out[ro + h] = f2bf((t[i] - mu) * inv * g[h] + bta[h]);
    }
}

// ---------------------------------------------------------------------------
extern "C" void kernel_launch(void* const* d_in, const int* in_sizes, int n_in,
                              void* d_out, int out_size, void* d_ws, size_t ws_size,
                              hipStream_t stream) {
    const int*   ids          = (const int*)d_in[0];
    const float* embed        = (const float*)d_in[1];
    const float* nm_gate_w    = (const float*)d_in[2];
    const float* nm_gate_b    = (const float*)d_in[3];
    const float* nm_filter_w  = (const float*)d_in[4];
    const float* nm_filter_b  = (const float*)d_in[5];
    const float* nm_ctx_w     = (const float*)d_in[6];
    const float* nm_ctx_b     = (const float*)d_in[7];
    const float* q_w          = (const float*)d_in[8];
    const float* q_b          = (const float*)d_in[9];
    const float* k_w          = (const float*)d_in[10];
    const float* k_b          = (const float*)d_in[11];
    const float* v_w          = (const float*)d_in[12];
    const float* v_b          = (const float*)d_in[13];
    const float* gain_w       = (const float*)d_in[14];
    const float* gain_b       = (const float*)d_in[15];
    const float* attn_ow      = (const float*)d_in[16];
    const float* attn_ob      = (const float*)d_in[17];
    const float* en_w         = (const float*)d_in[18];
    const float* en_b         = (const float*)d_in[19];
    const float* plastic_w    = (const float*)d_in[20];
    const float* fix_w        = (const float*)d_in[21];
    const float* fix_b        = (const float*)d_in[22];
    const float* ln_g         = (const float*)d_in[23];
    const float* ln_b         = (const float*)d_in[24];
    const float* out_w        = (const float*)d_in[25];
    const float* out_b        = (const float*)d_in[26];

    size_t T = (size_t)B_ * S_ * H_;      // 8.4M elements
    size_t need = 4 * T * sizeof(unsigned short)             // X,Qb,Kb,Vb
                + (size_t)H_ * H_ * sizeof(unsigned short)   // Wbf
                + ((size_t)B_ * H_ + 64) * sizeof(float);
    if (ws_size < need) return;  // diagnostic: output stays 0 -> absmax = max|ref|

    unsigned short* X   = (unsigned short*)d_ws;
    unsigned short* Qb  = X + T;
    unsigned short* Kb  = Qb + T;
    unsigned short* Vb  = Kb + T;
    unsigned short* Wbf = Vb + T;                 // H*H bf16 weight scratch
    float* xmean  = (float*)(Wbf + (size_t)H_ * H_);   // B*H
    float* dopnor = xmean + (size_t)B_ * H_;      // 2*B
    float* qscale = dopnor + 2 * B_;              // B*N

    const int M = B_ * S_;
    const int W8  = H_ * H_ / 8;                  // wcvt items for HxH
    const int WG  = (W8 + 255) / 256;
    const int W8o = V_ * H_ / 8;                  // for out_w
    const int WGo = (W8o + 255) / 256;

    gather_kernel<<<dim3((int)(T / 256)), 256, 0, stream>>>(ids, embed, X);

    hipMemsetAsync(xmean, 0, (size_t)B_ * H_ * sizeof(float), stream);
    mean_kernel<<<dim3(B_ * H_ / 256, 16), 256, 0, stream>>>(X, xmean);
    nm_kernel<<<1, 256, 0, stream>>>(xmean, nm_ctx_w, nm_ctx_b, dopnor);

    // Qb = X * (1 + dop * sigmoid(X @ gate_w^T + gate_b))
    wcvt_kernel<<<WG, 256, 0, stream>>>(nm_gate_w, Wbf, W8);
    gemm_bt<<<dim3(M / 128, H_ / 128), 256, 0, stream>>>(
        X, Wbf, nm_gate_b, Qb, X, dopnor, H_, H_, 1);
    // X = Qb + nor * tanh(Qb @ filter_w^T + filter_b)
    wcvt_kernel<<<WG, 256, 0, stream>>>(nm_filter_w, Wbf, W8);
    gemm_bt<<<dim3(M / 128, H_ / 128), 256, 0, stream>>>(
        Qb, Wbf, nm_filter_b, X, Qb, dopnor, H_, H_, 2);

    for (int l = 0; l < L_; l++) {
        size_t wo = (size_t)l * H_ * H_;
        size_t bo = (size_t)l * H_;
        hipMemsetAsync(xmean, 0, (size_t)B_ * H_ * sizeof(float), stream);
        mean_kernel<<<dim3(B_ * H_ / 256, 16), 256, 0, stream>>>(X, xmean);
        gain_kernel<<<1, 256, 0, stream>>>(xmean, gain_w + (size_t)l * N_ * H_,
                                           gain_b + (size_t)l * N_, qscale);

        wcvt_kernel<<<WG, 256, 0, stream>>>(q_w + wo, Wbf, W8);
        gemm_bt<<<dim3(M / 128, H_ / 128), 256, 0, stream>>>(
            X, Wbf, q_b + bo, Qb, nullptr, nullptr, H_, H_, 0);
        wcvt_kernel<<<WG, 256, 0, stream>>>(k_w + wo, Wbf, W8);
        gemm_bt<<<dim3(M / 128, H_ / 128), 256, 0, stream>>>(
            X, Wbf, k_b + bo, Kb, nullptr, nullptr, H_, H_, 0);
        wcvt_kernel<<<WG, 256, 0, stream>>>(v_w + wo, Wbf, W8);
        gemm_bt<<<dim3(M / 128, H_ / 128), 256, 0, stream>>>(
            X, Wbf, v_b + bo, Vb, nullptr, nullptr, H_, H_, 0);

        flash_attn<<<dim3(S_ / 64, B_ * N_), 256, 0, stream>>>(Qb, Kb, Vb, qscale, Qb);

        // Kb = X + (attn @ ow^T + ob)
        wcvt_kernel<<<WG, 256, 0, stream>>>(attn_ow + wo, Wbf, W8);
        gemm_bt<<<dim3(M / 128, H_ / 128), 256, 0, stream>>>(
            Qb, Wbf, attn_ob + bo, Kb, X, nullptr, H_, H_, 3);
        // Vb = silu(Kb @ en_w^T + en_b)
        wcvt_kernel<<<WG, 256, 0, stream>>>(en_w + wo, Wbf, W8);
        gemm_bt<<<dim3(M / 128, H_ / 128), 256, 0, stream>>>(
            Kb, Wbf, en_b + bo, Vb, nullptr, nullptr, H_, H_, 4);
        // Qb = Vb @ fix_w^T + fix_b ; Kb = Vb @ plastic_w^T
        wcvt_kernel<<<WG, 256, 0, stream>>>(fix_w + wo, Wbf, W8);
        gemm_bt<<<dim3(M / 128, H_ / 128), 256, 0, stream>>>(
            Vb, Wbf, fix_b + bo, Qb, nullptr, nullptr, H_, H_, 0);
        wcvt_kernel<<<WG, 256, 0, stream>>>(plastic_w + wo, Wbf, W8);
        gemm_bt<<<dim3(M / 128, H_ / 128), 256, 0, stream>>>(
            Vb, Wbf, nullptr, Kb, nullptr, nullptr, H_, H_, 0);
        // X = LN(Vb + Qb + Kb)
        ln_kernel<<<dim3(M), 256, 0, stream>>>(Vb, Qb, Kb, ln_g + bo, ln_b + bo, X);
    }

    // logits = X @ out_w^T + out_b  (fp32 out)
    wcvt_kernel<<<WGo, 256, 0, stream>>>(out_w, Wbf, W8o);
    gemm_bt<<<dim3(M / 128, V_ / 128), 256, 0, stream>>>(
        X, Wbf, out_b, (float*)d_out, nullptr, nullptr, H_, V_, 5);
}

// Round 4
// 2389.181 us; speedup vs baseline: 1.6008x; 1.6008x over previous
//
#include <hip/hip_runtime.h>

#define B_ 4
#define S_ 2048
#define H_ 1024
#define L_ 4
#define N_ 4
#define D_ 256
#define V_ 256
#define EPSF 1e-5f

typedef __attribute__((ext_vector_type(8))) short short8;
typedef __attribute__((ext_vector_type(4))) float f32x4;

__device__ inline float bf2f(unsigned short u) {
    union { unsigned int ui; float f; } c; c.ui = ((unsigned int)u) << 16; return c.f;
}
__device__ inline unsigned short f2bf(float f) {
    union { float f; unsigned int ui; } c; c.f = f;
    unsigned int u = c.ui;
    unsigned int r = (u + 0x7FFFu + ((u >> 16) & 1u)) >> 16;
    return (unsigned short)r;
}
__device__ inline float wave64_sum(float v) {
    for (int m = 32; m >= 1; m >>= 1) v += __shfl_xor(v, m, 64);
    return v;
}
// async global->LDS, 16B per lane; lds base must be wave-uniform
__device__ inline void gl_lds16(const unsigned short* g, unsigned short* l) {
    __builtin_amdgcn_global_load_lds(
        (const __attribute__((address_space(1))) unsigned int*)g,
        (__attribute__((address_space(3))) unsigned int*)l, 16, 0, 0);
}

// ---------------------------------------------------------------------------
// fp32 -> bf16 weight convert, 8 elements/thread
// ---------------------------------------------------------------------------
__global__ void wcvt_kernel(const float* __restrict__ W,
                            unsigned short* __restrict__ Wb, int n8) {
    int idx = blockIdx.x * 256 + threadIdx.x;
    if (idx >= n8) return;
    size_t base = (size_t)idx * 8;
    float4 a0 = *(const float4*)(W + base);
    float4 a1 = *(const float4*)(W + base + 4);
    short8 t;
    t[0] = f2bf(a0.x); t[1] = f2bf(a0.y); t[2] = f2bf(a0.z); t[3] = f2bf(a0.w);
    t[4] = f2bf(a1.x); t[5] = f2bf(a1.y); t[6] = f2bf(a1.z); t[7] = f2bf(a1.w);
    *(short8*)(Wb + base) = t;
}

// ---------------------------------------------------------------------------
// Embedding gather: fp32 embed -> bf16 X
// ---------------------------------------------------------------------------
__global__ void gather_kernel(const int* __restrict__ ids,
                              const float* __restrict__ embed,
                              unsigned short* __restrict__ x) {
    size_t idx = (size_t)blockIdx.x * 256 + threadIdx.x;   // T total
    int bs = (int)(idx >> 10);
    int h  = (int)(idx & 1023);
    x[idx] = f2bf(embed[(size_t)ids[bs] * H_ + h]);
}

// ---------------------------------------------------------------------------
// Column mean (accumulated as sum into fp32, divided later)
// ---------------------------------------------------------------------------
__global__ void mean_kernel(const unsigned short* __restrict__ Xin,
                            float* __restrict__ xmean) {
    int idx = blockIdx.x * 256 + threadIdx.x;   // 0 .. B*H-1
    int b = idx >> 10, h = idx & 1023;
    int s0 = blockIdx.y * 128;
    const unsigned short* p = Xin + ((size_t)b * S_ + s0) * H_ + h;
    float s = 0.f;
    for (int i = 0; i < 128; i++) s += bf2f(p[(size_t)i * H_]);
    atomicAdd(&xmean[idx], s);
}

// nm: dopnor[b*2+j] = dot(xmean[b]/S, nm_ctx_w[j]) + nm_ctx_b[j]   (fp32 w,b)
__global__ void nm_kernel(const float* __restrict__ xmean,
                          const float* __restrict__ w,
                          const float* __restrict__ bias,
                          float* __restrict__ dopnor) {
    int wave = threadIdx.x >> 6, lane = threadIdx.x & 63;
    for (int p = wave; p < 2 * B_; p += 4) {
        int b = p >> 1, j = p & 1;
        float s = 0.f;
        for (int h = lane; h < H_; h += 64) s += xmean[b * H_ + h] * w[j * H_ + h];
        s = wave64_sum(s);
        if (lane == 0) dopnor[p] = s / (float)S_ + bias[j];
    }
}

// gain: qscale[b*N+n] = (1 + dot(xmean[b]/S, gw[n]) + gb[n]) / sqrt(D)  (fp32)
__global__ void gain_kernel(const float* __restrict__ xmean,
                            const float* __restrict__ gw,
                            const float* __restrict__ gb,
                            float* __restrict__ qscale) {
    int wave = threadIdx.x >> 6, lane = threadIdx.x & 63;
    for (int p = wave; p < B_ * N_; p += 4) {
        int b = p >> 2, n = p & 3;
        float s = 0.f;
        for (int h = lane; h < H_; h += 64) s += xmean[b * H_ + h] * gw[n * H_ + h];
        s = wave64_sum(s);
        if (lane == 0) qscale[p] = (1.f + s / (float)S_ + gb[n]) * 0.0625f;
    }
}

// ---------------------------------------------------------------------------
// GEMM (m97 structure): C(MxN) = epilogue( A(MxK) @ W(NxK)^T + bias )
// 128x128 block tile, BK=32, LDS staging via global_load_lds width 16.
// 4 waves (2x2), wave = 64x64 via 4x4 mfma_f32_16x16x32_bf16.
// modes: 0 plain->bf16; 1 gate; 2 noise; 3 residual; 4 silu; 5 plain->fp32;
//        6 V^T store: Cout[((b*N+n)*D+d)*S + s] (bf16, packed short4)
// ---------------------------------------------------------------------------
__global__ __launch_bounds__(256) void gemm_bt(
    const unsigned short* __restrict__ A, const unsigned short* __restrict__ W,
    const float* __restrict__ bias, void* __restrict__ Cout,
    const unsigned short* __restrict__ X, const float* __restrict__ scal,
    int K, int Nout, int mode) {
    __shared__ unsigned short As[128 * 32];
    __shared__ unsigned short Bs[128 * 32];
    int tid = threadIdx.x;
    int wave = tid >> 6, lane = tid & 63;
    int quad = lane >> 4, l16 = lane & 15;
    int bm = blockIdx.x * 128;
    int bn = blockIdx.y * 128;
    int mw = (wave >> 1) * 64, nw = (wave & 1) * 64;

    // staging source: wave w round j covers rows j*64 + w*16 + lane/4, col (lane%4)*8
    const unsigned short* Ag = A + (size_t)(bm + wave * 16 + (lane >> 2)) * K + (lane & 3) * 8;
    const unsigned short* Wg = W + (size_t)(bn + wave * 16 + (lane >> 2)) * K + (lane & 3) * 8;
    unsigned short* ldsA = As + wave * 512;
    unsigned short* ldsB = Bs + wave * 512;
    size_t rowskip = (size_t)64 * K;

    f32x4 acc[4][4];
#pragma unroll
    for (int i = 0; i < 4; i++)
#pragma unroll
        for (int j = 0; j < 4; j++)
#pragma unroll
            for (int r = 0; r < 4; r++) acc[i][j][r] = 0.f;

    for (int kk = 0; kk < K; kk += 32) {
        __syncthreads();   // previous tile's readers done
        gl_lds16(Ag + kk, ldsA);
        gl_lds16(Ag + rowskip + kk, ldsA + 2048);
        gl_lds16(Wg + kk, ldsB);
        gl_lds16(Wg + rowskip + kk, ldsB + 2048);
        __syncthreads();   // drains vmcnt (loads landed)

        short8 af[4], bfr[4];
#pragma unroll
        for (int i = 0; i < 4; i++)
            af[i] = *(const short8*)&As[(mw + i * 16 + l16) * 32 + quad * 8];
#pragma unroll
        for (int j = 0; j < 4; j++)
            bfr[j] = *(const short8*)&Bs[(nw + j * 16 + l16) * 32 + quad * 8];
#pragma unroll
        for (int i = 0; i < 4; i++)
#pragma unroll
            for (int j = 0; j < 4; j++)
                acc[i][j] = __builtin_amdgcn_mfma_f32_16x16x32_bf16(af[i], bfr[j], acc[i][j], 0, 0, 0);
    }

    if (mode == 6) {
        // transposed store: col=h -> (n,d); 4 consecutive s packed per store
#pragma unroll
        for (int i = 0; i < 4; i++) {
#pragma unroll
            for (int j = 0; j < 4; j++) {
                int col = bn + nw + j * 16 + l16;
                float bv = bias ? bias[col] : 0.f;
                int n = col >> 8, d = col & 255;
                int row0 = bm + mw + i * 16 + quad * 4;
                int b = row0 >> 11, s0 = row0 & 2047;
                union { unsigned short u[4]; uint2 v; } pk;
#pragma unroll
                for (int r = 0; r < 4; r++) pk.u[r] = f2bf(acc[i][j][r] + bv);
                *(uint2*)((unsigned short*)Cout +
                          ((size_t)(b * N_ + n) * D_ + d) * S_ + s0) = pk.v;
            }
        }
        return;
    }

#pragma unroll
    for (int i = 0; i < 4; i++) {
#pragma unroll
        for (int j = 0; j < 4; j++) {
            int col = bn + nw + j * 16 + l16;
            float bv = bias ? bias[col] : 0.f;
#pragma unroll
            for (int r = 0; r < 4; r++) {
                int row = bm + mw + i * 16 + quad * 4 + r;
                float v = acc[i][j][r] + bv;
                size_t off = (size_t)row * Nout + col;
                if (mode == 5) {
                    ((float*)Cout)[off] = v;
                    continue;
                }
                float outv;
                if (mode == 0) {
                    outv = v;
                } else if (mode == 1) {
                    float sig = 1.f / (1.f + __expf(-v));
                    float dop = scal[(row >> 11) * 2];
                    outv = bf2f(X[off]) * (1.f + dop * sig);
                } else if (mode == 2) {
                    float nor = scal[(row >> 11) * 2 + 1];
                    outv = bf2f(X[off]) + nor * tanhf(v);
                } else if (mode == 3) {
                    outv = v + bf2f(X[off]);
                } else {
                    outv = v * (1.f / (1.f + __expf(-v)));
                }
                ((unsigned short*)Cout)[off] = f2bf(outv);
            }
        }
    }
}

// ---------------------------------------------------------------------------
// Flash attention: per (b,n), 64 q-rows/block (16/wave), TK=64.
// K staged [64][264] (row-major, padded); V^T (precomputed global [b][n][d][s])
// staged [256][72]. Conflict-free b128 staging. Out in-place to O (== Q buf).
// ---------------------------------------------------------------------------
__global__ __launch_bounds__(256) void flash_attn(
    const unsigned short* __restrict__ Q, const unsigned short* __restrict__ Kg,
    const unsigned short* __restrict__ VT, const float* __restrict__ qscale,
    unsigned short* __restrict__ O) {
    __shared__ unsigned short Kt[64][264];     // t x d, padded
    __shared__ unsigned short Vtl[256][72];    // d x t, padded
    __shared__ unsigned short Pl[4][16][72];   // per-wave P: m x t, padded

    int tid = threadIdx.x;
    int wave = tid >> 6, lane = tid & 63;
    int quad = lane >> 4, l16 = lane & 15;
    int bnh = blockIdx.y;          // b*N + n
    size_t base = ((size_t)(bnh >> 2) * S_) * H_ + (size_t)(bnh & 3) * D_;
    size_t vtbase = (size_t)bnh * D_ * S_;
    int qw = blockIdx.x * 64 + wave * 16;
    float scale = qscale[bnh];

    // Q fragments (8 k-steps of 32) for this wave's 16 q-rows
    short8 qf[8];
#pragma unroll
    for (int kk = 0; kk < 8; kk++)
        qf[kk] = *(const short8*)(Q + base + (size_t)(qw + l16) * H_ + kk * 32 + quad * 8);

    f32x4 o[16];
#pragma unroll
    for (int c = 0; c < 16; c++)
#pragma unroll
        for (int r = 0; r < 4; r++) o[c][r] = 0.f;
    float mrow[4] = {-1e30f, -1e30f, -1e30f, -1e30f};
    float lrow[4] = {0.f, 0.f, 0.f, 0.f};

    for (int t0 = 0; t0 < S_; t0 += 64) {
        __syncthreads();  // prior tile's readers done
        // stage K tile: 64 rows x 256 cols, 8 chunks of 16B per thread
#pragma unroll
        for (int rr = 0; rr < 8; rr++) {
            int c = rr * 256 + tid;
            int row = c >> 5, col = (c & 31) * 8;
            *(short8*)&Kt[row][col] =
                *(const short8*)(Kg + base + (size_t)(t0 + row) * H_ + col);
        }
        // stage V^T tile: 256 d-rows x 64 t-cols
#pragma unroll
        for (int rr = 0; rr < 8; rr++) {
            int c = rr * 256 + tid;
            int d = c >> 3, col = (c & 7) * 8;
            *(short8*)&Vtl[d][col] =
                *(const short8*)(VT + vtbase + (size_t)d * S_ + t0 + col);
        }
        __syncthreads();

        // scores S = Q K^T (16 x 64) as 4 col-tiles
        f32x4 s[4];
#pragma unroll
        for (int j = 0; j < 4; j++)
#pragma unroll
            for (int r = 0; r < 4; r++) s[j][r] = 0.f;
#pragma unroll
        for (int j = 0; j < 4; j++)
#pragma unroll
            for (int kk = 0; kk < 8; kk++) {
                short8 kf = *(const short8*)&Kt[j * 16 + l16][kk * 32 + quad * 8];
                s[j] = __builtin_amdgcn_mfma_f32_16x16x32_bf16(qf[kk], kf, s[j], 0, 0, 0);
            }

        // online softmax (row quad*4+r lives in this quad's 16 lanes)
        float alpha[4];
#pragma unroll
        for (int r = 0; r < 4; r++) {
            float sv[4];
#pragma unroll
            for (int j = 0; j < 4; j++) sv[j] = s[j][r] * scale;
            float mx = fmaxf(fmaxf(sv[0], sv[1]), fmaxf(sv[2], sv[3]));
            for (int m = 8; m >= 1; m >>= 1) mx = fmaxf(mx, __shfl_xor(mx, m, 64));
            float mnew = fmaxf(mrow[r], mx);
            alpha[r] = __expf(mrow[r] - mnew);
            mrow[r] = mnew;
            float rs = 0.f;
#pragma unroll
            for (int j = 0; j < 4; j++) {
                float p = __expf(sv[j] - mnew);
                rs += p;
                Pl[wave][quad * 4 + r][j * 16 + l16] = f2bf(p);
            }
            for (int m = 8; m >= 1; m >>= 1) rs += __shfl_xor(rs, m, 64);
            lrow[r] = lrow[r] * alpha[r] + rs;
        }
#pragma unroll
        for (int c = 0; c < 16; c++)
#pragma unroll
            for (int r = 0; r < 4; r++) o[c][r] *= alpha[r];

        // O += P V : P 16x64 from LDS (A-layout), V^T tiles as B
        short8 pf0 = *(const short8*)&Pl[wave][l16][quad * 8];
        short8 pf1 = *(const short8*)&Pl[wave][l16][32 + quad * 8];
#pragma unroll
        for (int c = 0; c < 16; c++) {
            short8 vf0 = *(const short8*)&Vtl[c * 16 + l16][quad * 8];
            o[c] = __builtin_amdgcn_mfma_f32_16x16x32_bf16(pf0, vf0, o[c], 0, 0, 0);
            short8 vf1 = *(const short8*)&Vtl[c * 16 + l16][32 + quad * 8];
            o[c] = __builtin_amdgcn_mfma_f32_16x16x32_bf16(pf1, vf1, o[c], 0, 0, 0);
        }
    }

    float invl[4];
#pragma unroll
    for (int r = 0; r < 4; r++) invl[r] = 1.f / lrow[r];
#pragma unroll
    for (int c = 0; c < 16; c++)
#pragma unroll
        for (int r = 0; r < 4; r++) {
            int row = qw + quad * 4 + r;
            int d = c * 16 + l16;
            O[base + (size_t)row * H_ + d] = f2bf(o[c][r] * invl[r]);
        }
}

// ---------------------------------------------------------------------------
// Fused t = xe + y1 + y2; LayerNorm(t) * g + b  -> out (bf16); g,b fp32
// ---------------------------------------------------------------------------
__global__ __launch_bounds__(256) void ln_kernel(
    const unsigned short* __restrict__ xe, const unsigned short* __restrict__ y1,
    const unsigned short* __restrict__ y2, const float* __restrict__ g,
    const float* __restrict__ bta, unsigned short* __restrict__ out) {
    int row = blockIdx.x;
    size_t ro = (size_t)row * H_;
    int tid = threadIdx.x;
    float t[4]; float s = 0.f, s2 = 0.f;
#pragma unroll
    for (int i = 0; i < 4; i++) {
        int h = i * 256 + tid;
        float v = bf2f(xe[ro + h]) + bf2f(y1[ro + h]) + bf2f(y2[ro + h]);
        t[i] = v; s += v; s2 += v * v;
    }
    s = wave64_sum(s); s2 = wave64_sum(s2);
    __shared__ float sh[8];
    int wave = tid >> 6, lane = tid & 63;
    if (lane == 0) { sh[wave] = s; sh[4 + wave] = s2; }
    __syncthreads();
    s  = sh[0] + sh[1] + sh[2] + sh[3];
    s2 = sh[4] + sh[5] + sh[6] + sh[7];
    float mu = s * (1.f / H_);
    float var = s2 * (1.f / H_) - mu * mu;
    float inv = rsqrtf(var + EPSF);
#pragma unroll
    for (int i = 0; i < 4; i++) {
        int h = i * 256 + tid;
        out[ro + h] = f2bf((t[i] - mu) * inv * g[h] + bta[h]);
    }
}

// ---------------------------------------------------------------------------
extern "C" void kernel_launch(void* const* d_in, const int* in_sizes, int n_in,
                              void* d_out, int out_size, void* d_ws, size_t ws_size,
                              hipStream_t stream) {
    const int*   ids          = (const int*)d_in[0];
    const float* embed        = (const float*)d_in[1];
    const float* nm_gate_w    = (const float*)d_in[2];
    const float* nm_gate_b    = (const float*)d_in[3];
    const float* nm_filter_w  = (const float*)d_in[4];
    const float* nm_filter_b  = (const float*)d_in[5];
    const float* nm_ctx_w     = (const float*)d_in[6];
    const float* nm_ctx_b     = (const float*)d_in[7];
    const float* q_w          = (const float*)d_in[8];
    const float* q_b          = (const float*)d_in[9];
    const float* k_w          = (const float*)d_in[10];
    const float* k_b          = (const float*)d_in[11];
    const float* v_w          = (const float*)d_in[12];
    const float* v_b          = (const float*)d_in[13];
    const float* gain_w       = (const float*)d_in[14];
    const float* gain_b       = (const float*)d_in[15];
    const float* attn_ow      = (const float*)d_in[16];
    const float* attn_ob      = (const float*)d_in[17];
    const float* en_w         = (const float*)d_in[18];
    const float* en_b         = (const float*)d_in[19];
    const float* plastic_w    = (const float*)d_in[20];
    const float* fix_w        = (const float*)d_in[21];
    const float* fix_b        = (const float*)d_in[22];
    const float* ln_g         = (const float*)d_in[23];
    const float* ln_b         = (const float*)d_in[24];
    const float* out_w        = (const float*)d_in[25];
    const float* out_b        = (const float*)d_in[26];

    size_t T = (size_t)B_ * S_ * H_;      // 8.4M elements
    size_t need = 4 * T * sizeof(unsigned short)             // X,Qb,Kb,Vb
                + (size_t)H_ * H_ * sizeof(unsigned short)   // Wbf
                + ((size_t)B_ * H_ + 64) * sizeof(float);
    if (ws_size < need) return;  // diagnostic: output stays 0 -> absmax = max|ref|

    unsigned short* X   = (unsigned short*)d_ws;
    unsigned short* Qb  = X + T;
    unsigned short* Kb  = Qb + T;
    unsigned short* Vb  = Kb + T;
    unsigned short* Wbf = Vb + T;                 // H*H bf16 weight scratch
    float* xmean  = (float*)(Wbf + (size_t)H_ * H_);   // B*H
    float* dopnor = xmean + (size_t)B_ * H_;      // 2*B
    float* qscale = dopnor + 2 * B_;              // B*N

    const int M = B_ * S_;
    const int W8  = H_ * H_ / 8;
    const int WG  = (W8 + 255) / 256;
    const int W8o = V_ * H_ / 8;
    const int WGo = (W8o + 255) / 256;

    gather_kernel<<<dim3((int)(T / 256)), 256, 0, stream>>>(ids, embed, X);

    hipMemsetAsync(xmean, 0, (size_t)B_ * H_ * sizeof(float), stream);
    mean_kernel<<<dim3(B_ * H_ / 256, 16), 256, 0, stream>>>(X, xmean);
    nm_kernel<<<1, 256, 0, stream>>>(xmean, nm_ctx_w, nm_ctx_b, dopnor);

    // Qb = X * (1 + dop * sigmoid(X @ gate_w^T + gate_b))
    wcvt_kernel<<<WG, 256, 0, stream>>>(nm_gate_w, Wbf, W8);
    gemm_bt<<<dim3(M / 128, H_ / 128), 256, 0, stream>>>(
        X, Wbf, nm_gate_b, Qb, X, dopnor, H_, H_, 1);
    // X = Qb + nor * tanh(Qb @ filter_w^T + filter_b)
    wcvt_kernel<<<WG, 256, 0, stream>>>(nm_filter_w, Wbf, W8);
    gemm_bt<<<dim3(M / 128, H_ / 128), 256, 0, stream>>>(
        Qb, Wbf, nm_filter_b, X, Qb, dopnor, H_, H_, 2);

    for (int l = 0; l < L_; l++) {
        size_t wo = (size_t)l * H_ * H_;
        size_t bo = (size_t)l * H_;
        hipMemsetAsync(xmean, 0, (size_t)B_ * H_ * sizeof(float), stream);
        mean_kernel<<<dim3(B_ * H_ / 256, 16), 256, 0, stream>>>(X, xmean);
        gain_kernel<<<1, 256, 0, stream>>>(xmean, gain_w + (size_t)l * N_ * H_,
                                           gain_b + (size_t)l * N_, qscale);

        wcvt_kernel<<<WG, 256, 0, stream>>>(q_w + wo, Wbf, W8);
        gemm_bt<<<dim3(M / 128, H_ / 128), 256, 0, stream>>>(
            X, Wbf, q_b + bo, Qb, nullptr, nullptr, H_, H_, 0);
        wcvt_kernel<<<WG, 256, 0, stream>>>(k_w + wo, Wbf, W8);
        gemm_bt<<<dim3(M / 128, H_ / 128), 256, 0, stream>>>(
            X, Wbf, k_b + bo, Kb, nullptr, nullptr, H_, H_, 0);
        // V projection -> transposed layout [b][n][d][s] in Vb
        wcvt_kernel<<<WG, 256, 0, stream>>>(v_w + wo, Wbf, W8);
        gemm_bt<<<dim3(M / 128, H_ / 128), 256, 0, stream>>>(
            X, Wbf, v_b + bo, Vb, nullptr, nullptr, H_, H_, 6);

        flash_attn<<<dim3(S_ / 64, B_ * N_), 256, 0, stream>>>(Qb, Kb, Vb, qscale, Qb);

        // Kb = X + (attn @ ow^T + ob)
        wcvt_kernel<<<WG, 256, 0, stream>>>(attn_ow + wo, Wbf, W8);
        gemm_bt<<<dim3(M / 128, H_ / 128), 256, 0, stream>>>(
            Qb, Wbf, attn_ob + bo, Kb, X, nullptr, H_, H_, 3);
        // Vb = silu(Kb @ en_w^T + en_b)
        wcvt_kernel<<<WG, 256, 0, stream>>>(en_w + wo, Wbf, W8);
        gemm_bt<<<dim3(M / 128, H_ / 128), 256, 0, stream>>>(
            Kb, Wbf, en_b + bo, Vb, nullptr, nullptr, H_, H_, 4);
        // Qb = Vb @ fix_w^T + fix_b ; Kb = Vb @ plastic_w^T
        wcvt_kernel<<<WG, 256, 0, stream>>>(fix_w + wo, Wbf, W8);
        gemm_bt<<<dim3(M / 128, H_ / 128), 256, 0, stream>>>(
            Vb, Wbf, fix_b + bo, Qb, nullptr, nullptr, H_, H_, 0);
        wcvt_kernel<<<WG, 256, 0, stream>>>(plastic_w + wo, Wbf, W8);
        gemm_bt<<<dim3(M / 128, H_ / 128), 256, 0, stream>>>(
            Vb, Wbf, nullptr, Kb, nullptr, nullptr, H_, H_, 0);
        // X = LN(Vb + Qb + Kb)
        ln_kernel<<<dim3(M), 256, 0, stream>>>(Vb, Qb, Kb, ln_g + bo, ln_b + bo, X);
    }

    // logits = X @ out_w^T + out_b  (fp32 out)
    wcvt_kernel<<<WGo, 256, 0, stream>>>(out_w, Wbf, W8o);
    gemm_bt<<<dim3(M / 128, V_ / 128), 256, 0, stream>>>(
        X, Wbf, out_b, (float*)d_out, nullptr, nullptr, H_, V_, 5);
}

// Round 5
// 1924.498 us; speedup vs baseline: 1.9873x; 1.2415x over previous
//
#include <hip/hip_runtime.h>

#define B_ 4
#define S_ 2048
#define H_ 1024
#define L_ 4
#define N_ 4
#define D_ 256
#define V_ 256
#define EPSF 1e-5f

typedef __attribute__((ext_vector_type(8))) short short8;
typedef __attribute__((ext_vector_type(4))) float f32x4;

__device__ inline float bf2f(unsigned short u) {
    union { unsigned int ui; float f; } c; c.ui = ((unsigned int)u) << 16; return c.f;
}
__device__ inline unsigned short f2bf(float f) {
    union { float f; unsigned int ui; } c; c.f = f;
    unsigned int u = c.ui;
    unsigned int r = (u + 0x7FFFu + ((u >> 16) & 1u)) >> 16;
    return (unsigned short)r;
}
__device__ inline float wave64_sum(float v) {
    for (int m = 32; m >= 1; m >>= 1) v += __shfl_xor(v, m, 64);
    return v;
}
// async global->LDS, 16B per lane; lds base must be wave-uniform
__device__ inline void gl_lds16(const unsigned short* g, unsigned short* l) {
    __builtin_amdgcn_global_load_lds(
        (const __attribute__((address_space(1))) unsigned int*)g,
        (__attribute__((address_space(3))) unsigned int*)l, 16, 0, 0);
}

// ---------------------------------------------------------------------------
// fp32 -> bf16 weight convert, 8 elements/thread
// ---------------------------------------------------------------------------
__global__ void wcvt_kernel(const float* __restrict__ W,
                            unsigned short* __restrict__ Wb, int n8) {
    int idx = blockIdx.x * 256 + threadIdx.x;
    if (idx >= n8) return;
    size_t base = (size_t)idx * 8;
    float4 a0 = *(const float4*)(W + base);
    float4 a1 = *(const float4*)(W + base + 4);
    short8 t;
    t[0] = f2bf(a0.x); t[1] = f2bf(a0.y); t[2] = f2bf(a0.z); t[3] = f2bf(a0.w);
    t[4] = f2bf(a1.x); t[5] = f2bf(a1.y); t[6] = f2bf(a1.z); t[7] = f2bf(a1.w);
    *(short8*)(Wb + base) = t;
}

// combined weight: Wo = bf16(Wa + Wb2 + I) per HxH layer (layers contiguous)
__global__ void wadd_kernel(const float* __restrict__ Wa, const float* __restrict__ Wb2,
                            unsigned short* __restrict__ Wo, int n8) {
    int idx = blockIdx.x * 256 + threadIdx.x;
    if (idx >= n8) return;
    size_t base = (size_t)idx * 8;
    short8 t;
#pragma unroll
    for (int e = 0; e < 8; e++) {
        size_t p = base + e;
        int pos = (int)(p & ((size_t)H_ * H_ - 1));   // within-layer offset
        float v = Wa[p] + Wb2[p] + (((pos >> 10) == (pos & (H_ - 1))) ? 1.f : 0.f);
        t[e] = f2bf(v);
    }
    *(short8*)(Wo + base) = t;
}

// ---------------------------------------------------------------------------
// Embedding gather: fp32 embed -> bf16 X
// ---------------------------------------------------------------------------
__global__ void gather_kernel(const int* __restrict__ ids,
                              const float* __restrict__ embed,
                              unsigned short* __restrict__ x) {
    size_t idx = (size_t)blockIdx.x * 256 + threadIdx.x;   // T total
    int bs = (int)(idx >> 10);
    int h  = (int)(idx & 1023);
    x[idx] = f2bf(embed[(size_t)ids[bs] * H_ + h]);
}

// ---------------------------------------------------------------------------
// Column mean (accumulated as sum into fp32, divided later)
// ---------------------------------------------------------------------------
__global__ void mean_kernel(const unsigned short* __restrict__ Xin,
                            float* __restrict__ xmean) {
    int idx = blockIdx.x * 256 + threadIdx.x;   // 0 .. B*H-1
    int b = idx >> 10, h = idx & 1023;
    int s0 = blockIdx.y * 128;
    const unsigned short* p = Xin + ((size_t)b * S_ + s0) * H_ + h;
    float s = 0.f;
    for (int i = 0; i < 128; i++) s += bf2f(p[(size_t)i * H_]);
    atomicAdd(&xmean[idx], s);
}

// nm: dopnor[b*2+j] = dot(xmean[b]/S, nm_ctx_w[j]) + nm_ctx_b[j]   (fp32 w,b)
__global__ void nm_kernel(const float* __restrict__ xmean,
                          const float* __restrict__ w,
                          const float* __restrict__ bias,
                          float* __restrict__ dopnor) {
    int wave = threadIdx.x >> 6, lane = threadIdx.x & 63;
    for (int p = wave; p < 2 * B_; p += 4) {
        int b = p >> 1, j = p & 1;
        float s = 0.f;
        for (int h = lane; h < H_; h += 64) s += xmean[b * H_ + h] * w[j * H_ + h];
        s = wave64_sum(s);
        if (lane == 0) dopnor[p] = s / (float)S_ + bias[j];
    }
}

// gain: qscale[b*N+n] = (1 + dot(xmean[b]/S, gw[n]) + gb[n]) / sqrt(D)  (fp32)
__global__ void gain_kernel(const float* __restrict__ xmean,
                            const float* __restrict__ gw,
                            const float* __restrict__ gb,
                            float* __restrict__ qscale) {
    int wave = threadIdx.x >> 6, lane = threadIdx.x & 63;
    for (int p = wave; p < B_ * N_; p += 4) {
        int b = p >> 2, n = p & 3;
        float s = 0.f;
        for (int h = lane; h < H_; h += 64) s += xmean[b * H_ + h] * gw[n * H_ + h];
        s = wave64_sum(s);
        if (lane == 0) qscale[p] = (1.f + s / (float)S_ + gb[n]) * 0.0625f;
    }
}

// ---------------------------------------------------------------------------
// GEMM (m97 structure): C(MxN) = epilogue( A(MxK) @ W(NxK)^T + bias )
// 128x128 block tile, BK=32, LDS staging via global_load_lds width 16.
// modes: 0 plain->bf16; 1 gate; 2 noise; 3 residual; 4 silu; 5 plain->fp32;
//        6 V^T store: Cout[((b*N+n)*D+d)*S + s] (bf16, packed short4)
// ---------------------------------------------------------------------------
__global__ __launch_bounds__(256) void gemm_bt(
    const unsigned short* __restrict__ A, const unsigned short* __restrict__ W,
    const float* __restrict__ bias, void* __restrict__ Cout,
    const unsigned short* __restrict__ X, const float* __restrict__ scal,
    int K, int Nout, int mode) {
    __shared__ unsigned short As[128 * 32];
    __shared__ unsigned short Bs[128 * 32];
    int tid = threadIdx.x;
    int wave = tid >> 6, lane = tid & 63;
    int quad = lane >> 4, l16 = lane & 15;
    int bm = blockIdx.x * 128;
    int bn = blockIdx.y * 128;
    int mw = (wave >> 1) * 64, nw = (wave & 1) * 64;

    const unsigned short* Ag = A + (size_t)(bm + wave * 16 + (lane >> 2)) * K + (lane & 3) * 8;
    const unsigned short* Wg = W + (size_t)(bn + wave * 16 + (lane >> 2)) * K + (lane & 3) * 8;
    unsigned short* ldsA = As + wave * 512;
    unsigned short* ldsB = Bs + wave * 512;
    size_t rowskip = (size_t)64 * K;

    f32x4 acc[4][4];
#pragma unroll
    for (int i = 0; i < 4; i++)
#pragma unroll
        for (int j = 0; j < 4; j++)
#pragma unroll
            for (int r = 0; r < 4; r++) acc[i][j][r] = 0.f;

    for (int kk = 0; kk < K; kk += 32) {
        __syncthreads();
        gl_lds16(Ag + kk, ldsA);
        gl_lds16(Ag + rowskip + kk, ldsA + 2048);
        gl_lds16(Wg + kk, ldsB);
        gl_lds16(Wg + rowskip + kk, ldsB + 2048);
        __syncthreads();

        short8 af[4], bfr[4];
#pragma unroll
        for (int i = 0; i < 4; i++)
            af[i] = *(const short8*)&As[(mw + i * 16 + l16) * 32 + quad * 8];
#pragma unroll
        for (int j = 0; j < 4; j++)
            bfr[j] = *(const short8*)&Bs[(nw + j * 16 + l16) * 32 + quad * 8];
#pragma unroll
        for (int i = 0; i < 4; i++)
#pragma unroll
            for (int j = 0; j < 4; j++)
                acc[i][j] = __builtin_amdgcn_mfma_f32_16x16x32_bf16(af[i], bfr[j], acc[i][j], 0, 0, 0);
    }

    if (mode == 6) {
#pragma unroll
        for (int i = 0; i < 4; i++) {
#pragma unroll
            for (int j = 0; j < 4; j++) {
                int col = bn + nw + j * 16 + l16;
                float bv = bias ? bias[col] : 0.f;
                int n = col >> 8, d = col & 255;
                int row0 = bm + mw + i * 16 + quad * 4;
                int b = row0 >> 11, s0 = row0 & 2047;
                union { unsigned short u[4]; uint2 v; } pk;
#pragma unroll
                for (int r = 0; r < 4; r++) pk.u[r] = f2bf(acc[i][j][r] + bv);
                *(uint2*)((unsigned short*)Cout +
                          ((size_t)(b * N_ + n) * D_ + d) * S_ + s0) = pk.v;
            }
        }
        return;
    }

#pragma unroll
    for (int i = 0; i < 4; i++) {
#pragma unroll
        for (int j = 0; j < 4; j++) {
            int col = bn + nw + j * 16 + l16;
            float bv = bias ? bias[col] : 0.f;
#pragma unroll
            for (int r = 0; r < 4; r++) {
                int row = bm + mw + i * 16 + quad * 4 + r;
                float v = acc[i][j][r] + bv;
                size_t off = (size_t)row * Nout + col;
                if (mode == 5) {
                    ((float*)Cout)[off] = v;
                    continue;
                }
                float outv;
                if (mode == 0) {
                    outv = v;
                } else if (mode == 1) {
                    float sig = 1.f / (1.f + __expf(-v));
                    float dop = scal[(row >> 11) * 2];
                    outv = bf2f(X[off]) * (1.f + dop * sig);
                } else if (mode == 2) {
                    float nor = scal[(row >> 11) * 2 + 1];
                    outv = bf2f(X[off]) + nor * tanhf(v);
                } else if (mode == 3) {
                    outv = v + bf2f(X[off]);
                } else {
                    outv = v * (1.f / (1.f + __expf(-v)));
                }
                ((unsigned short*)Cout)[off] = f2bf(outv);
            }
        }
    }
}

// ---------------------------------------------------------------------------
// Flash attention: per (b,n), 128 q-rows/block (8 waves x 16), TK=64.
// K staged [64][264]; V^T (global [b][n][d][s]) staged [272][72] where rows
// 256.. hold a ones-tile so row-sums accumulate in the MFMA accumulator
// (alpha-rescale applies automatically). Out in-place to O (== Q buffer).
// ---------------------------------------------------------------------------
__global__ __launch_bounds__(512) void flash_attn(
    const unsigned short* __restrict__ Q, const unsigned short* __restrict__ Kg,
    const unsigned short* __restrict__ VT, const float* __restrict__ qscale,
    unsigned short* __restrict__ O) {
    __shared__ unsigned short Kt[64][264];     // t x d, padded
    __shared__ unsigned short Vtl[272][72];    // d x t, padded; rows 256+ = ones-tile
    __shared__ unsigned short Pl[8][16][72];   // per-wave P: m x t, padded

    int tid = threadIdx.x;
    int wave = tid >> 6, lane = tid & 63;
    int quad = lane >> 4, l16 = lane & 15;
    int bnh = blockIdx.y;          // b*N + n
    size_t base = ((size_t)(bnh >> 2) * S_) * H_ + (size_t)(bnh & 3) * D_;
    size_t vtbase = (size_t)bnh * D_ * S_;
    int qw = blockIdx.x * 128 + wave * 16;
    float scale = qscale[bnh];

    // ones-tile init (rows 256..271): row 256 = 1.0, rest 0
    for (int c = tid; c < 16 * 72; c += 512) {
        int rr = c / 72, cc = c - rr * 72;
        Vtl[256 + rr][cc] = (rr == 0) ? (unsigned short)0x3F80 : (unsigned short)0;
    }

    // Q fragments (8 k-steps of 32) for this wave's 16 q-rows
    short8 qf[8];
#pragma unroll
    for (int kk = 0; kk < 8; kk++)
        qf[kk] = *(const short8*)(Q + base + (size_t)(qw + l16) * H_ + kk * 32 + quad * 8);

    f32x4 o[16], osum;
#pragma unroll
    for (int c = 0; c < 16; c++)
#pragma unroll
        for (int r = 0; r < 4; r++) o[c][r] = 0.f;
#pragma unroll
    for (int r = 0; r < 4; r++) osum[r] = 0.f;
    float mrow[4] = {-1e30f, -1e30f, -1e30f, -1e30f};

    for (int t0 = 0; t0 < S_; t0 += 64) {
        __syncthreads();  // prior tile's readers done (also orders ones-init)
        // stage K tile: 64 x 256, 4 chunks of 8 per thread
#pragma unroll
        for (int rr = 0; rr < 4; rr++) {
            int c = rr * 512 + tid;
            int row = c >> 5, col = (c & 31) * 8;
            *(short8*)&Kt[row][col] =
                *(const short8*)(Kg + base + (size_t)(t0 + row) * H_ + col);
        }
        // stage V^T tile: 256 d-rows x 64 t-cols
#pragma unroll
        for (int rr = 0; rr < 4; rr++) {
            int c = rr * 512 + tid;
            int d = c >> 3, col = (c & 7) * 8;
            *(short8*)&Vtl[d][col] =
                *(const short8*)(VT + vtbase + (size_t)d * S_ + t0 + col);
        }
        __syncthreads();

        // scores S = Q K^T (16 x 64) as 4 col-tiles
        f32x4 s[4];
#pragma unroll
        for (int j = 0; j < 4; j++)
#pragma unroll
            for (int r = 0; r < 4; r++) s[j][r] = 0.f;
#pragma unroll
        for (int j = 0; j < 4; j++)
#pragma unroll
            for (int kk = 0; kk < 8; kk++) {
                short8 kf = *(const short8*)&Kt[j * 16 + l16][kk * 32 + quad * 8];
                s[j] = __builtin_amdgcn_mfma_f32_16x16x32_bf16(qf[kk], kf, s[j], 0, 0, 0);
            }

        // online softmax: max via shuffles; sum via MFMA ones-tile
        float alpha[4];
#pragma unroll
        for (int r = 0; r < 4; r++) {
            float sv[4];
#pragma unroll
            for (int j = 0; j < 4; j++) sv[j] = s[j][r] * scale;
            float mx = fmaxf(fmaxf(sv[0], sv[1]), fmaxf(sv[2], sv[3]));
            for (int m = 8; m >= 1; m >>= 1) mx = fmaxf(mx, __shfl_xor(mx, m, 64));
            float mnew = fmaxf(mrow[r], mx);
            alpha[r] = __expf(mrow[r] - mnew);
            mrow[r] = mnew;
#pragma unroll
            for (int j = 0; j < 4; j++)
                Pl[wave][quad * 4 + r][j * 16 + l16] = f2bf(__expf(sv[j] - mnew));
        }
#pragma unroll
        for (int c = 0; c < 16; c++)
#pragma unroll
            for (int r = 0; r < 4; r++) o[c][r] *= alpha[r];
#pragma unroll
        for (int r = 0; r < 4; r++) osum[r] *= alpha[r];

        // O += P V ; row-sum tile accumulates l
        short8 pf0 = *(const short8*)&Pl[wave][l16][quad * 8];
        short8 pf1 = *(const short8*)&Pl[wave][l16][32 + quad * 8];
#pragma unroll
        for (int c = 0; c < 16; c++) {
            short8 vf0 = *(const short8*)&Vtl[c * 16 + l16][quad * 8];
            o[c] = __builtin_amdgcn_mfma_f32_16x16x32_bf16(pf0, vf0, o[c], 0, 0, 0);
            short8 vf1 = *(const short8*)&Vtl[c * 16 + l16][32 + quad * 8];
            o[c] = __builtin_amdgcn_mfma_f32_16x16x32_bf16(pf1, vf1, o[c], 0, 0, 0);
        }
        {
            short8 vs0 = *(const short8*)&Vtl[256 + l16][quad * 8];
            osum = __builtin_amdgcn_mfma_f32_16x16x32_bf16(pf0, vs0, osum, 0, 0, 0);
            short8 vs1 = *(const short8*)&Vtl[256 + l16][32 + quad * 8];
            osum = __builtin_amdgcn_mfma_f32_16x16x32_bf16(pf1, vs1, osum, 0, 0, 0);
        }
    }

    // l for row quad*4+r lives in lane (quad*16) col 0 of osum
    float invl[4];
#pragma unroll
    for (int r = 0; r < 4; r++)
        invl[r] = 1.f / __shfl(osum[r], (lane & 48), 64);
#pragma unroll
    for (int c = 0; c < 16; c++)
#pragma unroll
        for (int r = 0; r < 4; r++) {
            int row = qw + quad * 4 + r;
            int d = c * 16 + l16;
            O[base + (size_t)row * H_ + d] = f2bf(o[c][r] * invl[r]);
        }
}

// ---------------------------------------------------------------------------
// LayerNorm(y) * g + b -> out (bf16); g,b fp32
// ---------------------------------------------------------------------------
__global__ __launch_bounds__(256) void ln_kernel(
    const unsigned short* __restrict__ y, const float* __restrict__ g,
    const float* __restrict__ bta, unsigned short* __restrict__ out) {
    int row = blockIdx.x;
    size_t ro = (size_t)row * H_;
    int tid = threadIdx.x;
    float t[4]; float s = 0.f, s2 = 0.f;
#pragma unroll
    for (int i = 0; i < 4; i++) {
        int h = i * 256 + tid;
        float v = bf2f(y[ro + h]);
        t[i] = v; s += v; s2 += v * v;
    }
    s = wave64_sum(s); s2 = wave64_sum(s2);
    __shared__ float sh[8];
    int wave = tid >> 6, lane = tid & 63;
    if (lane == 0) { sh[wave] = s; sh[4 + wave] = s2; }
    __syncthreads();
    s  = sh[0] + sh[1] + sh[2] + sh[3];
    s2 = sh[4] + sh[5] + sh[6] + sh[7];
    float mu = s * (1.f / H_);
    float var = s2 * (1.f / H_) - mu * mu;
    float inv = rsqrtf(var + EPSF);
#pragma unroll
    for (int i = 0; i < 4; i++) {
        int h = i * 256 + tid;
        out[ro + h] = f2bf((t[i] - mu) * inv * g[h] + bta[h]);
    }
}

// ---------------------------------------------------------------------------
extern "C" void kernel_launch(void* const* d_in, const int* in_sizes, int n_in,
                              void* d_out, int out_size, void* d_ws, size_t ws_size,
                              hipStream_t stream) {
    const int*   ids          = (const int*)d_in[0];
    const float* embed        = (const float*)d_in[1];
    const float* nm_gate_w    = (const float*)d_in[2];
    const float* nm_gate_b    = (const float*)d_in[3];
    const float* nm_filter_w  = (const float*)d_in[4];
    const float* nm_filter_b  = (const float*)d_in[5];
    const float* nm_ctx_w     = (const float*)d_in[6];
    const float* nm_ctx_b     = (const float*)d_in[7];
    const float* q_w          = (const float*)d_in[8];
    const float* q_b          = (const float*)d_in[9];
    const float* k_w          = (const float*)d_in[10];
    const float* k_b          = (const float*)d_in[11];
    const float* v_w          = (const float*)d_in[12];
    const float* v_b          = (const float*)d_in[13];
    const float* gain_w       = (const float*)d_in[14];
    const float* gain_b       = (const float*)d_in[15];
    const float* attn_ow      = (const float*)d_in[16];
    const float* attn_ob      = (const float*)d_in[17];
    const float* en_w         = (const float*)d_in[18];
    const float* en_b         = (const float*)d_in[19];
    const float* plastic_w    = (const float*)d_in[20];
    const float* fix_w        = (const float*)d_in[21];
    const float* fix_b        = (const float*)d_in[22];
    const float* ln_g         = (const float*)d_in[23];
    const float* ln_b         = (const float*)d_in[24];
    const float* out_w        = (const float*)d_in[25];
    const float* out_b        = (const float*)d_in[26];

    size_t T  = (size_t)B_ * S_ * H_;      // 8.4M elements
    size_t WH = (size_t)H_ * H_;
    size_t smallBytes = ((size_t)B_ * H_ + 2 * B_ + B_ * N_ + 8) * sizeof(float);
    size_t megaElems  = 26 * WH + WH / 4;  // gate,filter + 6*4 per-layer + out
    size_t need_base  = 4 * T * 2 + smallBytes + 2 * WH;
    size_t need_mega  = 4 * T * 2 + smallBytes + 2 * megaElems;
    if (ws_size < need_base) return;  // diagnostic: absmax = max|ref|
    bool mega = ws_size >= need_mega;

    unsigned short* X   = (unsigned short*)d_ws;
    unsigned short* Qb  = X + T;
    unsigned short* Kb  = Qb + T;
    unsigned short* Vb  = Kb + T;
    float* xmean  = (float*)(Vb + T);             // B*H
    float* dopnor = xmean + (size_t)B_ * H_;      // 2*B
    float* qscale = dopnor + 2 * B_;              // B*N
    unsigned short* Wbase = (unsigned short*)(qscale + B_ * N_ + 8);
#define WOFF(k) (Wbase + (size_t)(k) * WH)

    const int M   = B_ * S_;
    const int W8  = (int)(WH / 8);                // HxH
    const int WG  = (W8 + 255) / 256;
    const int W84 = (int)(4 * WH / 8);            // L x HxH
    const int WG4 = (W84 + 255) / 256;
    const int W8o = V_ * H_ / 8;
    const int WGo = (W8o + 255) / 256;

    if (mega) {   // one-shot conversion of all weights
        wcvt_kernel<<<WG,  256, 0, stream>>>(nm_gate_w,   WOFF(0),  W8);
        wcvt_kernel<<<WG,  256, 0, stream>>>(nm_filter_w, WOFF(1),  W8);
        wcvt_kernel<<<WG4, 256, 0, stream>>>(q_w,         WOFF(2),  W84);
        wcvt_kernel<<<WG4, 256, 0, stream>>>(k_w,         WOFF(6),  W84);
        wcvt_kernel<<<WG4, 256, 0, stream>>>(v_w,         WOFF(10), W84);
        wcvt_kernel<<<WG4, 256, 0, stream>>>(attn_ow,     WOFF(14), W84);
        wcvt_kernel<<<WG4, 256, 0, stream>>>(en_w,        WOFF(18), W84);
        wadd_kernel<<<WG4, 256, 0, stream>>>(fix_w, plastic_w, WOFF(22), W84);
        wcvt_kernel<<<WGo, 256, 0, stream>>>(out_w,       WOFF(26), W8o);
    }

    gather_kernel<<<dim3((int)(T / 256)), 256, 0, stream>>>(ids, embed, X);

    hipMemsetAsync(xmean, 0, (size_t)B_ * H_ * sizeof(float), stream);
    mean_kernel<<<dim3(B_ * H_ / 256, 16), 256, 0, stream>>>(X, xmean);
    nm_kernel<<<1, 256, 0, stream>>>(xmean, nm_ctx_w, nm_ctx_b, dopnor);

    // Qb = X * (1 + dop * sigmoid(X @ gate_w^T + gate_b))
    const unsigned short* Wp;
    if (mega) Wp = WOFF(0);
    else { wcvt_kernel<<<WG, 256, 0, stream>>>(nm_gate_w, Wbase, W8); Wp = Wbase; }
    gemm_bt<<<dim3(M / 128, H_ / 128), 256, 0, stream>>>(
        X, Wp, nm_gate_b, Qb, X, dopnor, H_, H_, 1);
    // X = Qb + nor * tanh(Qb @ filter_w^T + filter_b)
    if (mega) Wp = WOFF(1);
    else { wcvt_kernel<<<WG, 256, 0, stream>>>(nm_filter_w, Wbase, W8); Wp = Wbase; }
    gemm_bt<<<dim3(M / 128, H_ / 128), 256, 0, stream>>>(
        Qb, Wp, nm_filter_b, X, Qb, dopnor, H_, H_, 2);

    for (int l = 0; l < L_; l++) {
        size_t wo = (size_t)l * WH;
        size_t bo = (size_t)l * H_;
        hipMemsetAsync(xmean, 0, (size_t)B_ * H_ * sizeof(float), stream);
        mean_kernel<<<dim3(B_ * H_ / 256, 16), 256, 0, stream>>>(X, xmean);
        gain_kernel<<<1, 256, 0, stream>>>(xmean, gain_w + (size_t)l * N_ * H_,
                                           gain_b + (size_t)l * N_, qscale);

        if (mega) Wp = WOFF(2) + wo;
        else { wcvt_kernel<<<WG, 256, 0, stream>>>(q_w + wo, Wbase, W8); Wp = Wbase; }
        gemm_bt<<<dim3(M / 128, H_ / 128), 256, 0, stream>>>(
            X, Wp, q_b + bo, Qb, nullptr, nullptr, H_, H_, 0);
        if (mega) Wp = WOFF(6) + wo;
        else { wcvt_kernel<<<WG, 256, 0, stream>>>(k_w + wo, Wbase, W8); Wp = Wbase; }
        gemm_bt<<<dim3(M / 128, H_ / 128), 256, 0, stream>>>(
            X, Wp, k_b + bo, Kb, nullptr, nullptr, H_, H_, 0);
        // V projection -> transposed layout [b][n][d][s]
        if (mega) Wp = WOFF(10) + wo;
        else { wcvt_kernel<<<WG, 256, 0, stream>>>(v_w + wo, Wbase, W8); Wp = Wbase; }
        gemm_bt<<<dim3(M / 128, H_ / 128), 256, 0, stream>>>(
            X, Wp, v_b + bo, Vb, nullptr, nullptr, H_, H_, 6);

        flash_attn<<<dim3(S_ / 128, B_ * N_), 512, 0, stream>>>(Qb, Kb, Vb, qscale, Qb);

        // Kb = X + (attn @ ow^T + ob)
        if (mega) Wp = WOFF(14) + wo;
        else { wcvt_kernel<<<WG, 256, 0, stream>>>(attn_ow + wo, Wbase, W8); Wp = Wbase; }
        gemm_bt<<<dim3(M / 128, H_ / 128), 256, 0, stream>>>(
            Qb, Wp, attn_ob + bo, Kb, X, nullptr, H_, H_, 3);
        // Vb = silu(Kb @ en_w^T + en_b)
        if (mega) Wp = WOFF(18) + wo;
        else { wcvt_kernel<<<WG, 256, 0, stream>>>(en_w + wo, Wbase, W8); Wp = Wbase; }
        gemm_bt<<<dim3(M / 128, H_ / 128), 256, 0, stream>>>(
            Kb, Wp, en_b + bo, Vb, nullptr, nullptr, H_, H_, 4);
        // Qb = Vb @ (I + fix + plastic)^T + fix_b   (folded residual)
        if (mega) Wp = WOFF(22) + wo;
        else { wadd_kernel<<<WG, 256, 0, stream>>>(fix_w + wo, plastic_w + wo, Wbase, W8); Wp = Wbase; }
        gemm_bt<<<dim3(M / 128, H_ / 128), 256, 0, stream>>>(
            Vb, Wp, fix_b + bo, Qb, nullptr, nullptr, H_, H_, 0);
        // X = LN(Qb)
        ln_kernel<<<dim3(M), 256, 0, stream>>>(Qb, ln_g + bo, ln_b + bo, X);
    }

    // logits = X @ out_w^T + out_b  (fp32 out)
    if (mega) Wp = WOFF(26);
    else { wcvt_kernel<<<WGo, 256, 0, stream>>>(out_w, Wbase, W8o); Wp = Wbase; }
    gemm_bt<<<dim3(M / 128, V_ / 128), 256, 0, stream>>>(
        X, Wp, out_b, (float*)d_out, nullptr, nullptr, H_, V_, 5);
#undef WOFF
}